// Round 15
// baseline (360.501 us; speedup 1.0000x reference)
//
#include <hip/hip_runtime.h>
#include <hip/hip_bf16.h>
#include <math.h>

// ---------------------------------------------------------------------------
// AudioVQMix. r8-verified kernels (best measured: 89.7us) with the histogram
// folded into the VQ kernels as direct global atomics (hist dispatch removed).
// Wave VQ = 2-term bf16-split MFMA GEMM (926 TF effective = simple-K-loop
// structural ceiling), wave-pair code-split. mfcc = 3-term-split MFMA
// transform + f32 l2norm + 3-term-split MFMA VQ, pair-split.
// Output (f32): [0..131071] encodings, then wave_ppl, wave_loss, mfcc_ppl,
// mfcc_loss.
// ---------------------------------------------------------------------------

#define NROWS 65536
#define DW    80
#define KW    1024
#define DM    38
#define KM    256

typedef __attribute__((ext_vector_type(8))) short bf16x8;
typedef __attribute__((ext_vector_type(4))) float f32x4;

__device__ __forceinline__ void bf16split(float v, short& h, short& l) {
    __hip_bfloat16 hb = __float2bfloat16(v);
    float hf = __bfloat162float(hb);
    __hip_bfloat16 lb = __float2bfloat16(v - hf);
    h = *(short*)&hb;
    l = *(short*)&lb;
}

__device__ __forceinline__ void bf16split3(float v, short& a, short& b, short& c) {
    __hip_bfloat16 h = __float2bfloat16(v);
    float hf = __bfloat162float(h);
    float r = v - hf;
    __hip_bfloat16 m = __float2bfloat16(r);
    float mf = __bfloat162float(m);
    __hip_bfloat16 lo = __float2bfloat16(r - mf);
    a = *(short*)&h; b = *(short*)&m; c = *(short*)&lo;
}

__device__ __forceinline__ bf16x8 bf8zero() {
    bf16x8 z;
    #pragma unroll
    for (int j = 0; j < 8; ++j) z[j] = 0;
    return z;
}

// workspace layout (bytes)
#define WS_SUMS   0        // 2 f32
#define WS_HIST   256      // 1280 i32 = 5120
#define WS_CNW    5376     // 1024 f32 = 4096
#define WS_CNM    9472     // 256 f32 = 1024
#define WS_CTF    10496    // 3 x 3840 shorts = 23040
#define WS_CBF    33536    // 3 x 12288 shorts = 73728
#define WS_CWH    107264   // 12288 frags x 8 shorts x 2B = 196608
#define WS_CWL    303872   // 196608  (end 500480)

// ---------------------------------------------------------------------------
// Prep (r7-verified, unchanged).
// ---------------------------------------------------------------------------
__global__ __launch_bounds__(256) void prep_kernel(
    const float* __restrict__ cbw, const float* __restrict__ cbm,
    float* __restrict__ sums, int* __restrict__ hist,
    float* __restrict__ cn_w, float* __restrict__ cn_m,
    short* __restrict__ ctf, short* __restrict__ cbf,
    short* __restrict__ cwh, short* __restrict__ cwl)
{
    int idx = blockIdx.x * 256 + threadIdx.x;
    if (idx < 12288) {
        const int f = idx;
        const int ct = f / 192, rem = f % 192, s = rem >> 6, l = rem & 63;
        const int code = ct * 16 + (l & 15);
        const int k0 = 32 * s + 8 * (l >> 4);
        bf16x8 h, lo;
        if (k0 < DW) {
            const float4* p = (const float4*)(cbw + (size_t)code * DW + k0);
            float4 u = p[0], v = p[1];
            float fv[8] = {u.x, u.y, u.z, u.w, v.x, v.y, v.z, v.w};
            #pragma unroll
            for (int j = 0; j < 8; ++j) {
                short hh, ll;
                bf16split(fv[j], hh, ll);
                h[j] = hh; lo[j] = ll;
            }
        } else { h = bf8zero(); lo = bf8zero(); }
        *(bf16x8*)&cwh[(size_t)f * 8] = h;
        *(bf16x8*)&cwl[(size_t)f * 8] = lo;
    } else if (idx < 16128) {
        int t = idx - 12288;
        int col, k;
        if (t < 3072) {
            int j = t & 7, l = (t >> 3) & 63, tt = t >> 9;
            col = (tt >> 1) * 16 + (l & 15);
            k = 32 * (tt & 1) + 8 * (l >> 4) + j;
        } else {
            int i2 = t - 3072;
            int j = i2 & 7, l = (i2 >> 3) & 31, ct = i2 >> 8;
            col = ct * 16 + (l & 15);
            k = 64 + 8 * (l >> 4) + j;
        }
        float v = (col < DM)
            ? (float)cos(2.0 * 3.14159265358979323846 * (double)((col + 2) * k) / 80.0)
            : 0.f;
        short a, b, c; bf16split3(v, a, b, c);
        ctf[t] = a; ctf[3840 + t] = b; ctf[7680 + t] = c;
    } else if (idx < 28416) {
        int i3 = idx - 16128;
        int code, k;
        if (i3 < 8192) {
            int j = i3 & 7, l = (i3 >> 3) & 63, ct = i3 >> 9;
            code = ct * 16 + (l & 15);
            k = 8 * (l >> 4) + j;
        } else {
            int i4 = i3 - 8192;
            int j = i4 & 7, l = (i4 >> 3) & 31, ct = i4 >> 8;
            code = ct * 16 + (l & 15);
            k = 32 + 8 * (l >> 4) + j;
        }
        float v = (k < DM) ? cbm[(size_t)code * DM + k] : 0.f;
        short a, b, c; bf16split3(v, a, b, c);
        cbf[i3] = a; cbf[12288 + i3] = b; cbf[24576 + i3] = c;
    } else if (idx < 29440) {
        int i = idx - 28416;
        const float* p = cbw + (size_t)i * DW;
        float s = 0.f;
        for (int k = 0; k < DW; ++k) s = fmaf(p[k], p[k], s);
        cn_w[i] = s;
    } else if (idx < 29696) {
        int i = idx - 29440;
        const float* p = cbm + (size_t)i * DM;
        float s = 0.f;
        for (int j = 0; j < DM; ++j) s = fmaf(p[j], p[j], s);
        cn_m[i] = s;
    } else if (idx < 30976) {
        hist[idx - 29696] = 0;
    } else if (idx == 30976) sums[0] = 0.f;
    else if (idx == 30977)   sums[1] = 0.f;
}

// ---------------------------------------------------------------------------
// Wave VQ (r8-verified, 55.6us). Block = 4 waves / 128 rows. Waves (2g,2g+1)
// share row group g; half h scans codes [h*512, h*512+512). + inline hist.
// ---------------------------------------------------------------------------
__global__ __launch_bounds__(256, 2) void wave_vq_mfma(
    const float* __restrict__ X, const short* __restrict__ cwh,
    const short* __restrict__ cwl, const float* __restrict__ cn,
    float* __restrict__ out, float* __restrict__ sums,
    int* __restrict__ hist)
{
    __shared__ float sd[2][64][16];
    __shared__ int   si[2][64][16];
    __shared__ float redw[2];

    const int tid  = threadIdx.x;
    const int l    = tid & 63;
    const int qu   = tid >> 6;
    const int grp  = qu >> 1;
    const int half = qu & 1;
    const int c16  = l & 15;
    const int g    = l >> 4;
    const size_t rowbase = (size_t)blockIdx.x * 128 + (size_t)grp * 64;

    bf16x8 Ah[4][3], Al[4][3];
    float xs2[4] = {0.f, 0.f, 0.f, 0.f};
    #pragma unroll
    for (int rt = 0; rt < 4; ++rt) {
        #pragma unroll
        for (int s = 0; s < 3; ++s) {
            const int k0 = 32 * s + 8 * g;
            bf16x8 ah, al;
            if (k0 < DW) {
                const float4* ap =
                    (const float4*)(X + (rowbase + rt * 16 + c16) * DW + k0);
                float4 u = ap[0], w = ap[1];
                float f[8] = {u.x, u.y, u.z, u.w, w.x, w.y, w.z, w.w};
                #pragma unroll
                for (int j = 0; j < 8; ++j) {
                    short hh, ll;
                    bf16split(f[j], hh, ll);
                    ah[j] = hh; al[j] = ll;
                    xs2[rt] = fmaf(f[j], f[j], xs2[rt]);
                }
            } else {
                ah = bf8zero(); al = bf8zero();
            }
            Ah[rt][s] = ah; Al[rt][s] = al;
        }
    }
    #pragma unroll
    for (int rt = 0; rt < 4; ++rt) {
        xs2[rt] += __shfl_xor(xs2[rt], 16, 64);
        xs2[rt] += __shfl_xor(xs2[rt], 32, 64);
    }

    float bd[4][4];
    int   bi[4][4];
    #pragma unroll
    for (int rt = 0; rt < 4; ++rt)
        #pragma unroll
        for (int i = 0; i < 4; ++i) { bd[rt][i] = 3.4e38f; bi[rt][i] = 0; }

    const bf16x8* Hp = (const bf16x8*)cwh + l;
    const bf16x8* Lp = (const bf16x8*)cwl + l;
    const int ct0 = half * 32;

    bf16x8 pbh[3], pbl[3];
    float pcn;
    #pragma unroll
    for (int s = 0; s < 3; ++s) {
        pbh[s] = Hp[(ct0 * 3 + s) * 64];
        pbl[s] = Lp[(ct0 * 3 + s) * 64];
    }
    pcn = cn[ct0 * 16 + c16];

    #pragma unroll 1
    for (int ctl = 0; ctl < 32; ++ctl) {
        const int ct = ct0 + ctl;
        bf16x8 bh[3], bl[3];
        #pragma unroll
        for (int s = 0; s < 3; ++s) { bh[s] = pbh[s]; bl[s] = pbl[s]; }
        const float cnv = pcn;
        if (ctl < 31) {
            #pragma unroll
            for (int s = 0; s < 3; ++s) {
                pbh[s] = Hp[((ct + 1) * 3 + s) * 64];
                pbl[s] = Lp[((ct + 1) * 3 + s) * 64];
            }
            pcn = cn[(ct + 1) * 16 + c16];
        }

        f32x4 acc[4];
        #pragma unroll
        for (int rt = 0; rt < 4; ++rt) acc[rt] = (f32x4){0.f, 0.f, 0.f, 0.f};
        #pragma unroll
        for (int s = 0; s < 3; ++s) {
            #pragma unroll
            for (int rt = 0; rt < 4; ++rt)
                acc[rt] = __builtin_amdgcn_mfma_f32_16x16x32_bf16(Al[rt][s], bl[s], acc[rt], 0, 0, 0);
            #pragma unroll
            for (int rt = 0; rt < 4; ++rt)
                acc[rt] = __builtin_amdgcn_mfma_f32_16x16x32_bf16(Ah[rt][s], bl[s], acc[rt], 0, 0, 0);
            #pragma unroll
            for (int rt = 0; rt < 4; ++rt)
                acc[rt] = __builtin_amdgcn_mfma_f32_16x16x32_bf16(Al[rt][s], bh[s], acc[rt], 0, 0, 0);
            #pragma unroll
            for (int rt = 0; rt < 4; ++rt)
                acc[rt] = __builtin_amdgcn_mfma_f32_16x16x32_bf16(Ah[rt][s], bh[s], acc[rt], 0, 0, 0);
        }
        const int idxbase = ct * 16 + c16;
        #pragma unroll
        for (int rt = 0; rt < 4; ++rt) {
            #pragma unroll
            for (int i = 0; i < 4; ++i) {
                float d = fmaf(-2.f, acc[rt][i], cnv);
                if (d < bd[rt][i]) { bd[rt][i] = d; bi[rt][i] = idxbase; }
            }
        }
    }

    if (half == 1) {
        #pragma unroll
        for (int rt = 0; rt < 4; ++rt)
            #pragma unroll
            for (int i = 0; i < 4; ++i) {
                sd[grp][l][rt * 4 + i] = bd[rt][i];
                si[grp][l][rt * 4 + i] = bi[rt][i];
            }
    }
    __syncthreads();
    if (half == 0) {
        float lw = 0.f;
        #pragma unroll
        for (int rt = 0; rt < 4; ++rt) {
            #pragma unroll
            for (int i = 0; i < 4; ++i) {
                float d = bd[rt][i]; int ix = bi[rt][i];
                float dp = sd[grp][l][rt * 4 + i];
                int   ip = si[grp][l][rt * 4 + i];
                if (dp < d || (dp == d && ip < ix)) { d = dp; ix = ip; }
                #pragma unroll
                for (int m = 1; m < 16; m <<= 1) {
                    float d2 = __shfl_xor(d, m, 64);
                    int   i2 = __shfl_xor(ix, m, 64);
                    if (d2 < d || (d2 == d && i2 < ix)) { d = d2; ix = i2; }
                }
                float xn = __shfl(xs2[rt], (l & 48) + 4 * (l >> 4) + i, 64);
                if (c16 == 0) {
                    size_t row = rowbase + rt * 16 + 4 * g + i;
                    out[2 * row] = (float)ix;
                    atomicAdd(&hist[ix], 1);
                    lw += d + xn;
                }
            }
        }
        #pragma unroll
        for (int m = 1; m < 64; m <<= 1) lw += __shfl_xor(lw, m, 64);
        if (l == 0) redw[grp] = lw;
    }
    __syncthreads();
    if (tid == 0) atomicAdd(&sums[0], redw[0] + redw[1]);
}

// ---------------------------------------------------------------------------
// MFCC (r8-verified). Block = 4 waves / 128 rows, pair-split. + inline hist.
// ---------------------------------------------------------------------------
__global__ __launch_bounds__(256, 2) void mfcc_mfma(
    const float* __restrict__ X, const float* __restrict__ cn_m,
    const short* __restrict__ ctf, const short* __restrict__ cbf,
    float* __restrict__ out, float* __restrict__ sums,
    int* __restrict__ hist)
{
    __shared__ float XF[2][64 * 49];
    __shared__ float sd[2][64][16];
    __shared__ int   si[2][64][16];
    __shared__ float CN[KM];
    __shared__ float red2[2];

    const int tid  = threadIdx.x;
    const int l    = tid & 63;
    const int qu   = tid >> 6;
    const int grp  = qu >> 1;
    const int half = qu & 1;
    const int c16  = l & 15;
    const int g    = l >> 4;
    const size_t rowbase = (size_t)blockIdx.x * 128 + (size_t)grp * 64;

    CN[tid] = cn_m[tid];

    float* xfl = &XF[grp][0];

    #pragma unroll 1
    for (int rt2 = 0; rt2 < 2; ++rt2) {
        const int rt = half * 2 + rt2;
        bf16x8 A0[3], A1[3], A2[3];
        #pragma unroll
        for (int s = 0; s < 3; ++s) {
            const int k0 = 32 * s + 8 * g;
            if (k0 < DW) {
                const float4* ap =
                    (const float4*)(X + (rowbase + rt * 16 + c16) * DW + k0);
                float4 u = ap[0], v = ap[1];
                float f[8] = {u.x, u.y, u.z, u.w, v.x, v.y, v.z, v.w};
                bf16x8 a0, a1, a2;
                #pragma unroll
                for (int j = 0; j < 8; ++j) {
                    short aa, bb, cc;
                    bf16split3(f[j], aa, bb, cc);
                    a0[j] = aa; a1[j] = bb; a2[j] = cc;
                }
                A0[s] = a0; A1[s] = a1; A2[s] = a2;
            } else {
                A0[s] = bf8zero(); A1[s] = bf8zero(); A2[s] = bf8zero();
            }
        }

        f32x4 accA[3], accB[3];
        #pragma unroll
        for (int ct = 0; ct < 3; ++ct) {
            accA[ct] = (f32x4){0.f, 0.f, 0.f, 0.f};
            accB[ct] = (f32x4){0.f, 0.f, 0.f, 0.f};
        }

        #pragma unroll
        for (int s = 0; s < 3; ++s) {
            #pragma unroll
            for (int ct = 0; ct < 3; ++ct) {
                bf16x8 b0, b1, b2;
                if (s < 2) {
                    const int off = ((ct * 2 + s) * 64 + l) * 8;
                    b0 = *(const bf16x8*)&ctf[off];
                    b1 = *(const bf16x8*)&ctf[3840 + off];
                    b2 = *(const bf16x8*)&ctf[7680 + off];
                } else if (l < 32) {
                    const int off = 3072 + (ct * 32 + l) * 8;
                    b0 = *(const bf16x8*)&ctf[off];
                    b1 = *(const bf16x8*)&ctf[3840 + off];
                    b2 = *(const bf16x8*)&ctf[7680 + off];
                } else {
                    b0 = bf8zero(); b1 = bf8zero(); b2 = bf8zero();
                }
                accA[ct] = __builtin_amdgcn_mfma_f32_16x16x32_bf16(A2[s], b0, accA[ct], 0, 0, 0);
                accA[ct] = __builtin_amdgcn_mfma_f32_16x16x32_bf16(A1[s], b1, accA[ct], 0, 0, 0);
                accA[ct] = __builtin_amdgcn_mfma_f32_16x16x32_bf16(A0[s], b2, accA[ct], 0, 0, 0);
                accB[ct] = __builtin_amdgcn_mfma_f32_16x16x32_bf16(A1[s], b0, accB[ct], 0, 0, 0);
                accB[ct] = __builtin_amdgcn_mfma_f32_16x16x32_bf16(A0[s], b1, accB[ct], 0, 0, 0);
                accB[ct] = __builtin_amdgcn_mfma_f32_16x16x32_bf16(A0[s], b0, accB[ct], 0, 0, 0);
            }
        }

        f32x4 acc[3];
        #pragma unroll
        for (int ct = 0; ct < 3; ++ct) acc[ct] = accA[ct] + accB[ct];

        #pragma unroll
        for (int i = 0; i < 4; ++i) {
            float n2 = acc[0][i] * acc[0][i];
            n2 = fmaf(acc[1][i], acc[1][i], n2);
            n2 = fmaf(acc[2][i], acc[2][i], n2);
            #pragma unroll
            for (int m = 1; m < 16; m <<= 1) n2 += __shfl_xor(n2, m, 64);
            float inv = 1.0f / fmaxf(sqrtf(n2), 1e-12f);
            const int row_l = rt * 16 + 4 * g + i;
            #pragma unroll
            for (int ct = 0; ct < 3; ++ct)
                xfl[row_l * 49 + ct * 16 + c16] = acc[ct][i] * inv;
        }
    }
    __syncthreads();

    bf16x8 X0[4][3], X1[4][3];
    #pragma unroll
    for (int rt = 0; rt < 4; ++rt) {
        const int r0 = rt * 16 + c16;
        {
            const float* p = &xfl[r0 * 49 + 8 * g];
            bf16x8 q0, q1, q2;
            #pragma unroll
            for (int j = 0; j < 8; ++j) {
                short aa, bb, cc;
                bf16split3(p[j], aa, bb, cc);
                q0[j] = aa; q1[j] = bb; q2[j] = cc;
            }
            X0[rt][0] = q0; X0[rt][1] = q1; X0[rt][2] = q2;
        }
        if (g < 2) {
            const float* p = &xfl[r0 * 49 + 32 + 8 * g];
            bf16x8 q0, q1, q2;
            #pragma unroll
            for (int j = 0; j < 8; ++j) {
                short aa, bb, cc;
                bf16split3(p[j], aa, bb, cc);
                q0[j] = aa; q1[j] = bb; q2[j] = cc;
            }
            X1[rt][0] = q0; X1[rt][1] = q1; X1[rt][2] = q2;
        } else {
            X1[rt][0] = bf8zero(); X1[rt][1] = bf8zero(); X1[rt][2] = bf8zero();
        }
    }

    float bd[4][4];
    int   bi[4][4];
    #pragma unroll
    for (int rt = 0; rt < 4; ++rt)
        #pragma unroll
        for (int i = 0; i < 4; ++i) { bd[rt][i] = 3.4e38f; bi[rt][i] = 0; }

    #pragma unroll 1
    for (int ctl = 0; ctl < 8; ++ctl) {
        const int ct = half * 8 + ctl;
        bf16x8 B0[3], B1[3];
        const int off0 = (ct * 64 + l) * 8;
        B0[0] = *(const bf16x8*)&cbf[off0];
        B0[1] = *(const bf16x8*)&cbf[12288 + off0];
        B0[2] = *(const bf16x8*)&cbf[24576 + off0];
        if (l < 32) {
            const int off1 = 8192 + (ct * 32 + l) * 8;
            B1[0] = *(const bf16x8*)&cbf[off1];
            B1[1] = *(const bf16x8*)&cbf[12288 + off1];
            B1[2] = *(const bf16x8*)&cbf[24576 + off1];
        } else {
            B1[0] = bf8zero(); B1[1] = bf8zero(); B1[2] = bf8zero();
        }
        const float cnv = CN[ct * 16 + c16];
        const int idxbase = ct * 16 + c16;
        #pragma unroll
        for (int rt = 0; rt < 4; ++rt) {
            f32x4 p0 = (f32x4){0.f, 0.f, 0.f, 0.f};
            f32x4 q0 = (f32x4){0.f, 0.f, 0.f, 0.f};
            f32x4 p1 = (f32x4){0.f, 0.f, 0.f, 0.f};
            f32x4 q1 = (f32x4){0.f, 0.f, 0.f, 0.f};
            p0 = __builtin_amdgcn_mfma_f32_16x16x32_bf16(X0[rt][2], B0[0], p0, 0, 0, 0);
            p0 = __builtin_amdgcn_mfma_f32_16x16x32_bf16(X0[rt][1], B0[1], p0, 0, 0, 0);
            p0 = __builtin_amdgcn_mfma_f32_16x16x32_bf16(X0[rt][0], B0[2], p0, 0, 0, 0);
            q0 = __builtin_amdgcn_mfma_f32_16x16x32_bf16(X0[rt][1], B0[0], q0, 0, 0, 0);
            q0 = __builtin_amdgcn_mfma_f32_16x16x32_bf16(X0[rt][0], B0[1], q0, 0, 0, 0);
            q0 = __builtin_amdgcn_mfma_f32_16x16x32_bf16(X0[rt][0], B0[0], q0, 0, 0, 0);
            p1 = __builtin_amdgcn_mfma_f32_16x16x32_bf16(X1[rt][2], B1[0], p1, 0, 0, 0);
            p1 = __builtin_amdgcn_mfma_f32_16x16x32_bf16(X1[rt][1], B1[1], p1, 0, 0, 0);
            p1 = __builtin_amdgcn_mfma_f32_16x16x32_bf16(X1[rt][0], B1[2], p1, 0, 0, 0);
            q1 = __builtin_amdgcn_mfma_f32_16x16x32_bf16(X1[rt][1], B1[0], q1, 0, 0, 0);
            q1 = __builtin_amdgcn_mfma_f32_16x16x32_bf16(X1[rt][0], B1[1], q1, 0, 0, 0);
            q1 = __builtin_amdgcn_mfma_f32_16x16x32_bf16(X1[rt][0], B1[0], q1, 0, 0, 0);
            #pragma unroll
            for (int i = 0; i < 4; ++i) {
                float d = fmaf(-2.f, (p0[i] + q0[i]) + (p1[i] + q1[i]), cnv);
                if (d < bd[rt][i]) { bd[rt][i] = d; bi[rt][i] = idxbase; }
            }
        }
    }

    if (half == 1) {
        #pragma unroll
        for (int rt = 0; rt < 4; ++rt)
            #pragma unroll
            for (int i = 0; i < 4; ++i) {
                sd[grp][l][rt * 4 + i] = bd[rt][i];
                si[grp][l][rt * 4 + i] = bi[rt][i];
            }
    }
    __syncthreads();
    if (half == 0) {
        float lm = 0.f;
        #pragma unroll
        for (int rt = 0; rt < 4; ++rt) {
            #pragma unroll
            for (int i = 0; i < 4; ++i) {
                float d = bd[rt][i]; int ix = bi[rt][i];
                float dp = sd[grp][l][rt * 4 + i];
                int   ip = si[grp][l][rt * 4 + i];
                if (dp < d || (dp == d && ip < ix)) { d = dp; ix = ip; }
                #pragma unroll
                for (int m = 1; m < 16; m <<= 1) {
                    float d2 = __shfl_xor(d, m, 64);
                    int   i2 = __shfl_xor(ix, m, 64);
                    if (d2 < d || (d2 == d && i2 < ix)) { d = d2; ix = i2; }
                }
                if (c16 == 0) {
                    size_t row = rowbase + rt * 16 + 4 * g + i;
                    out[2 * row + 1] = (float)(ix + KW);
                    atomicAdd(&hist[1024 + ix], 1);
                    lm += d + 1.0f;      // ||xf||^2 == 1
                }
            }
        }
        #pragma unroll
        for (int m = 1; m < 64; m <<= 1) lm += __shfl_xor(lm, m, 64);
        if (l == 0) red2[grp] = lm;
    }
    __syncthreads();
    if (tid == 0) atomicAdd(&sums[1], red2[0] + red2[1]);
}

__global__ __launch_bounds__(256) void finalize_kernel(
    const int* __restrict__ hist, const float* __restrict__ sums,
    float* __restrict__ out)
{
    __shared__ float red[4];
    const int tid = threadIdx.x;
    const bool wv = (blockIdx.x == 0);
    const int K = wv ? KW : KM;
    const int base = wv ? 0 : 1024;
    float s = 0.f;
    for (int i = tid; i < K; i += 256) {
        float p = (float)hist[base + i] * (1.0f / 65536.0f);
        s += p * logf(p + 1e-10f);
    }
    #pragma unroll
    for (int off = 32; off >= 1; off >>= 1) s += __shfl_xor(s, off, 64);
    if ((tid & 63) == 0) red[tid >> 6] = s;
    __syncthreads();
    if (tid == 0) {
        float t = red[0] + red[1] + red[2] + red[3];
        float ppl = expf(-t);
        float denom = wv ? (float)(NROWS * DW) : (float)(NROWS * DM);
        int obase = 2 * NROWS + (wv ? 0 : 2);
        out[obase]     = ppl;
        out[obase + 1] = 1.25f * sums[wv ? 0 : 1] / denom;
    }
}

extern "C" void kernel_launch(void* const* d_in, const int* in_sizes, int n_in,
                              void* d_out, int out_size, void* d_ws, size_t ws_size,
                              hipStream_t stream) {
    const float* X   = (const float*)d_in[0];
    const float* cbw = (const float*)d_in[1];
    const float* cbm = (const float*)d_in[2];
    float* out = (float*)d_out;

    char* ws = (char*)d_ws;
    float* sums = (float*)(ws + WS_SUMS);
    int*   hist = (int*)(ws + WS_HIST);
    float* cn_w = (float*)(ws + WS_CNW);
    float* cn_m = (float*)(ws + WS_CNM);
    short* ctf  = (short*)(ws + WS_CTF);
    short* cbf  = (short*)(ws + WS_CBF);
    short* cwh  = (short*)(ws + WS_CWH);
    short* cwl  = (short*)(ws + WS_CWL);

    prep_kernel<<<122, 256, 0, stream>>>(cbw, cbm, sums, hist, cn_w, cn_m,
                                         ctf, cbf, cwh, cwl);
    wave_vq_mfma<<<NROWS / 128, 256, 0, stream>>>(X, cwh, cwl, cn_w, out,
                                                  sums, hist);
    mfcc_mfma<<<NROWS / 128, 256, 0, stream>>>(X, cn_m, ctf, cbf, out,
                                               sums, hist);
    finalize_kernel<<<2, 256, 0, stream>>>(hist, sums, out);
}

// Round 16
// 89.853 us; speedup vs baseline: 4.0121x; 4.0121x over previous
//
#include <hip/hip_runtime.h>
#include <hip/hip_bf16.h>
#include <math.h>

// ---------------------------------------------------------------------------
// AudioVQMix — round-8 configuration (measured best: 89.7us), restored.
// Wave VQ = 2-term bf16-split MFMA GEMM (926 TF effective, at the ~900 TF
// simple-K-loop structural ceiling), wave-pair code-split. mfcc = 3-term
// split MFMA transform + f32 l2norm + 3-term VQ, pair-split. Histogram via
// LDS-aggregated hist_kernel (global-atomic contention on the 256-bin mfcc
// range makes inline per-row atomics catastrophic — r15 lesson).
// Output (f32): [0..131071] encodings, then wave_ppl, wave_loss, mfcc_ppl,
// mfcc_loss.
// ---------------------------------------------------------------------------

#define NROWS 65536
#define DW    80
#define KW    1024
#define DM    38
#define KM    256

typedef __attribute__((ext_vector_type(8))) short bf16x8;
typedef __attribute__((ext_vector_type(4))) float f32x4;

__device__ __forceinline__ void bf16split(float v, short& h, short& l) {
    __hip_bfloat16 hb = __float2bfloat16(v);
    float hf = __bfloat162float(hb);
    __hip_bfloat16 lb = __float2bfloat16(v - hf);
    h = *(short*)&hb;
    l = *(short*)&lb;
}

__device__ __forceinline__ void bf16split3(float v, short& a, short& b, short& c) {
    __hip_bfloat16 h = __float2bfloat16(v);
    float hf = __bfloat162float(h);
    float r = v - hf;
    __hip_bfloat16 m = __float2bfloat16(r);
    float mf = __bfloat162float(m);
    __hip_bfloat16 lo = __float2bfloat16(r - mf);
    a = *(short*)&h; b = *(short*)&m; c = *(short*)&lo;
}

__device__ __forceinline__ bf16x8 bf8zero() {
    bf16x8 z;
    #pragma unroll
    for (int j = 0; j < 8; ++j) z[j] = 0;
    return z;
}

// workspace layout (bytes)
#define WS_SUMS   0        // 2 f32
#define WS_HIST   256      // 1280 i32 = 5120
#define WS_CNW    5376     // 1024 f32 = 4096
#define WS_CNM    9472     // 256 f32 = 1024
#define WS_CTF    10496    // 3 x 3840 shorts = 23040
#define WS_CBF    33536    // 3 x 12288 shorts = 73728
#define WS_CWH    107264   // 12288 frags x 8 shorts x 2B = 196608
#define WS_CWL    303872   // 196608  (end 500480)

// ---------------------------------------------------------------------------
// Prep (r7-verified, unchanged).
// ---------------------------------------------------------------------------
__global__ __launch_bounds__(256) void prep_kernel(
    const float* __restrict__ cbw, const float* __restrict__ cbm,
    float* __restrict__ sums, int* __restrict__ hist,
    float* __restrict__ cn_w, float* __restrict__ cn_m,
    short* __restrict__ ctf, short* __restrict__ cbf,
    short* __restrict__ cwh, short* __restrict__ cwl)
{
    int idx = blockIdx.x * 256 + threadIdx.x;
    if (idx < 12288) {
        const int f = idx;
        const int ct = f / 192, rem = f % 192, s = rem >> 6, l = rem & 63;
        const int code = ct * 16 + (l & 15);
        const int k0 = 32 * s + 8 * (l >> 4);
        bf16x8 h, lo;
        if (k0 < DW) {
            const float4* p = (const float4*)(cbw + (size_t)code * DW + k0);
            float4 u = p[0], v = p[1];
            float fv[8] = {u.x, u.y, u.z, u.w, v.x, v.y, v.z, v.w};
            #pragma unroll
            for (int j = 0; j < 8; ++j) {
                short hh, ll;
                bf16split(fv[j], hh, ll);
                h[j] = hh; lo[j] = ll;
            }
        } else { h = bf8zero(); lo = bf8zero(); }
        *(bf16x8*)&cwh[(size_t)f * 8] = h;
        *(bf16x8*)&cwl[(size_t)f * 8] = lo;
    } else if (idx < 16128) {
        int t = idx - 12288;
        int col, k;
        if (t < 3072) {
            int j = t & 7, l = (t >> 3) & 63, tt = t >> 9;
            col = (tt >> 1) * 16 + (l & 15);
            k = 32 * (tt & 1) + 8 * (l >> 4) + j;
        } else {
            int i2 = t - 3072;
            int j = i2 & 7, l = (i2 >> 3) & 31, ct = i2 >> 8;
            col = ct * 16 + (l & 15);
            k = 64 + 8 * (l >> 4) + j;
        }
        float v = (col < DM)
            ? (float)cos(2.0 * 3.14159265358979323846 * (double)((col + 2) * k) / 80.0)
            : 0.f;
        short a, b, c; bf16split3(v, a, b, c);
        ctf[t] = a; ctf[3840 + t] = b; ctf[7680 + t] = c;
    } else if (idx < 28416) {
        int i3 = idx - 16128;
        int code, k;
        if (i3 < 8192) {
            int j = i3 & 7, l = (i3 >> 3) & 63, ct = i3 >> 9;
            code = ct * 16 + (l & 15);
            k = 8 * (l >> 4) + j;
        } else {
            int i4 = i3 - 8192;
            int j = i4 & 7, l = (i4 >> 3) & 31, ct = i4 >> 8;
            code = ct * 16 + (l & 15);
            k = 32 + 8 * (l >> 4) + j;
        }
        float v = (k < DM) ? cbm[(size_t)code * DM + k] : 0.f;
        short a, b, c; bf16split3(v, a, b, c);
        cbf[i3] = a; cbf[12288 + i3] = b; cbf[24576 + i3] = c;
    } else if (idx < 29440) {
        int i = idx - 28416;
        const float* p = cbw + (size_t)i * DW;
        float s = 0.f;
        for (int k = 0; k < DW; ++k) s = fmaf(p[k], p[k], s);
        cn_w[i] = s;
    } else if (idx < 29696) {
        int i = idx - 29440;
        const float* p = cbm + (size_t)i * DM;
        float s = 0.f;
        for (int j = 0; j < DM; ++j) s = fmaf(p[j], p[j], s);
        cn_m[i] = s;
    } else if (idx < 30976) {
        hist[idx - 29696] = 0;
    } else if (idx == 30976) sums[0] = 0.f;
    else if (idx == 30977)   sums[1] = 0.f;
}

// ---------------------------------------------------------------------------
// Wave VQ (r8-verified, 55.6us). Block = 4 waves / 128 rows. Waves (2g,2g+1)
// share row group g; wave half h scans codes [h*512, h*512+512).
// ---------------------------------------------------------------------------
__global__ __launch_bounds__(256, 2) void wave_vq_mfma(
    const float* __restrict__ X, const short* __restrict__ cwh,
    const short* __restrict__ cwl, const float* __restrict__ cn,
    float* __restrict__ out, float* __restrict__ sums)
{
    __shared__ float sd[2][64][16];
    __shared__ int   si[2][64][16];
    __shared__ float redw[2];

    const int tid  = threadIdx.x;
    const int l    = tid & 63;
    const int qu   = tid >> 6;
    const int grp  = qu >> 1;
    const int half = qu & 1;
    const int c16  = l & 15;
    const int g    = l >> 4;
    const size_t rowbase = (size_t)blockIdx.x * 128 + (size_t)grp * 64;

    bf16x8 Ah[4][3], Al[4][3];
    float xs2[4] = {0.f, 0.f, 0.f, 0.f};
    #pragma unroll
    for (int rt = 0; rt < 4; ++rt) {
        #pragma unroll
        for (int s = 0; s < 3; ++s) {
            const int k0 = 32 * s + 8 * g;
            bf16x8 ah, al;
            if (k0 < DW) {
                const float4* ap =
                    (const float4*)(X + (rowbase + rt * 16 + c16) * DW + k0);
                float4 u = ap[0], w = ap[1];
                float f[8] = {u.x, u.y, u.z, u.w, w.x, w.y, w.z, w.w};
                #pragma unroll
                for (int j = 0; j < 8; ++j) {
                    short hh, ll;
                    bf16split(f[j], hh, ll);
                    ah[j] = hh; al[j] = ll;
                    xs2[rt] = fmaf(f[j], f[j], xs2[rt]);
                }
            } else {
                ah = bf8zero(); al = bf8zero();
            }
            Ah[rt][s] = ah; Al[rt][s] = al;
        }
    }
    #pragma unroll
    for (int rt = 0; rt < 4; ++rt) {
        xs2[rt] += __shfl_xor(xs2[rt], 16, 64);
        xs2[rt] += __shfl_xor(xs2[rt], 32, 64);
    }

    float bd[4][4];
    int   bi[4][4];
    #pragma unroll
    for (int rt = 0; rt < 4; ++rt)
        #pragma unroll
        for (int i = 0; i < 4; ++i) { bd[rt][i] = 3.4e38f; bi[rt][i] = 0; }

    const bf16x8* Hp = (const bf16x8*)cwh + l;
    const bf16x8* Lp = (const bf16x8*)cwl + l;
    const int ct0 = half * 32;

    bf16x8 pbh[3], pbl[3];
    float pcn;
    #pragma unroll
    for (int s = 0; s < 3; ++s) {
        pbh[s] = Hp[(ct0 * 3 + s) * 64];
        pbl[s] = Lp[(ct0 * 3 + s) * 64];
    }
    pcn = cn[ct0 * 16 + c16];

    #pragma unroll 1
    for (int ctl = 0; ctl < 32; ++ctl) {
        const int ct = ct0 + ctl;
        bf16x8 bh[3], bl[3];
        #pragma unroll
        for (int s = 0; s < 3; ++s) { bh[s] = pbh[s]; bl[s] = pbl[s]; }
        const float cnv = pcn;
        if (ctl < 31) {
            #pragma unroll
            for (int s = 0; s < 3; ++s) {
                pbh[s] = Hp[((ct + 1) * 3 + s) * 64];
                pbl[s] = Lp[((ct + 1) * 3 + s) * 64];
            }
            pcn = cn[(ct + 1) * 16 + c16];
        }

        f32x4 acc[4];
        #pragma unroll
        for (int rt = 0; rt < 4; ++rt) acc[rt] = (f32x4){0.f, 0.f, 0.f, 0.f};
        #pragma unroll
        for (int s = 0; s < 3; ++s) {
            #pragma unroll
            for (int rt = 0; rt < 4; ++rt)
                acc[rt] = __builtin_amdgcn_mfma_f32_16x16x32_bf16(Al[rt][s], bl[s], acc[rt], 0, 0, 0);
            #pragma unroll
            for (int rt = 0; rt < 4; ++rt)
                acc[rt] = __builtin_amdgcn_mfma_f32_16x16x32_bf16(Ah[rt][s], bl[s], acc[rt], 0, 0, 0);
            #pragma unroll
            for (int rt = 0; rt < 4; ++rt)
                acc[rt] = __builtin_amdgcn_mfma_f32_16x16x32_bf16(Al[rt][s], bh[s], acc[rt], 0, 0, 0);
            #pragma unroll
            for (int rt = 0; rt < 4; ++rt)
                acc[rt] = __builtin_amdgcn_mfma_f32_16x16x32_bf16(Ah[rt][s], bh[s], acc[rt], 0, 0, 0);
        }
        const int idxbase = ct * 16 + c16;
        #pragma unroll
        for (int rt = 0; rt < 4; ++rt) {
            #pragma unroll
            for (int i = 0; i < 4; ++i) {
                float d = fmaf(-2.f, acc[rt][i], cnv);
                if (d < bd[rt][i]) { bd[rt][i] = d; bi[rt][i] = idxbase; }
            }
        }
    }

    // cross-wave combine: odd half publishes, even half merges (odd indices
    // all >= 512, so even wins ties naturally -> first-min semantics).
    if (half == 1) {
        #pragma unroll
        for (int rt = 0; rt < 4; ++rt)
            #pragma unroll
            for (int i = 0; i < 4; ++i) {
                sd[grp][l][rt * 4 + i] = bd[rt][i];
                si[grp][l][rt * 4 + i] = bi[rt][i];
            }
    }
    __syncthreads();
    if (half == 0) {
        float lw = 0.f;
        #pragma unroll
        for (int rt = 0; rt < 4; ++rt) {
            #pragma unroll
            for (int i = 0; i < 4; ++i) {
                float d = bd[rt][i]; int ix = bi[rt][i];
                float dp = sd[grp][l][rt * 4 + i];
                int   ip = si[grp][l][rt * 4 + i];
                if (dp < d || (dp == d && ip < ix)) { d = dp; ix = ip; }
                #pragma unroll
                for (int m = 1; m < 16; m <<= 1) {
                    float d2 = __shfl_xor(d, m, 64);
                    int   i2 = __shfl_xor(ix, m, 64);
                    if (d2 < d || (d2 == d && i2 < ix)) { d = d2; ix = i2; }
                }
                float xn = __shfl(xs2[rt], (l & 48) + 4 * (l >> 4) + i, 64);
                if (c16 == 0) {
                    size_t row = rowbase + rt * 16 + 4 * g + i;
                    out[2 * row] = (float)ix;
                    lw += d + xn;
                }
            }
        }
        #pragma unroll
        for (int m = 1; m < 64; m <<= 1) lw += __shfl_xor(lw, m, 64);
        if (l == 0) redw[grp] = lw;
    }
    __syncthreads();
    if (tid == 0) atomicAdd(&sums[0], redw[0] + redw[1]);
}

// ---------------------------------------------------------------------------
// MFCC (r8-verified). Block = 4 waves / 128 rows. Wave pair shares row group:
// transform rt-tiles split (half h does rt = 2h, 2h+1), VQ codes split
// (half h scans ct [8h, 8h+8)). Cross-wave combine as in wave kernel.
// ---------------------------------------------------------------------------
__global__ __launch_bounds__(256, 2) void mfcc_mfma(
    const float* __restrict__ X, const float* __restrict__ cn_m,
    const short* __restrict__ ctf, const short* __restrict__ cbf,
    float* __restrict__ out, float* __restrict__ sums)
{
    __shared__ float XF[2][64 * 49];             // 25088 B
    __shared__ float sd[2][64][16];
    __shared__ int   si[2][64][16];
    __shared__ float CN[KM];
    __shared__ float red2[2];

    const int tid  = threadIdx.x;
    const int l    = tid & 63;
    const int qu   = tid >> 6;
    const int grp  = qu >> 1;
    const int half = qu & 1;
    const int c16  = l & 15;
    const int g    = l >> 4;
    const size_t rowbase = (size_t)blockIdx.x * 128 + (size_t)grp * 64;

    CN[tid] = cn_m[tid];

    float* xfl = &XF[grp][0];

    // ---- transform: this wave's 2 rt-tiles ----
    #pragma unroll 1
    for (int rt2 = 0; rt2 < 2; ++rt2) {
        const int rt = half * 2 + rt2;
        bf16x8 A0[3], A1[3], A2[3];
        #pragma unroll
        for (int s = 0; s < 3; ++s) {
            const int k0 = 32 * s + 8 * g;
            if (k0 < DW) {
                const float4* ap =
                    (const float4*)(X + (rowbase + rt * 16 + c16) * DW + k0);
                float4 u = ap[0], v = ap[1];
                float f[8] = {u.x, u.y, u.z, u.w, v.x, v.y, v.z, v.w};
                bf16x8 a0, a1, a2;
                #pragma unroll
                for (int j = 0; j < 8; ++j) {
                    short aa, bb, cc;
                    bf16split3(f[j], aa, bb, cc);
                    a0[j] = aa; a1[j] = bb; a2[j] = cc;
                }
                A0[s] = a0; A1[s] = a1; A2[s] = a2;
            } else {
                A0[s] = bf8zero(); A1[s] = bf8zero(); A2[s] = bf8zero();
            }
        }

        f32x4 acc[3];
        #pragma unroll
        for (int ct = 0; ct < 3; ++ct) acc[ct] = (f32x4){0.f, 0.f, 0.f, 0.f};

        #pragma unroll
        for (int s = 0; s < 3; ++s) {
            #pragma unroll
            for (int ct = 0; ct < 3; ++ct) {
                bf16x8 b0, b1, b2;
                if (s < 2) {
                    const int off = ((ct * 2 + s) * 64 + l) * 8;
                    b0 = *(const bf16x8*)&ctf[off];
                    b1 = *(const bf16x8*)&ctf[3840 + off];
                    b2 = *(const bf16x8*)&ctf[7680 + off];
                } else if (l < 32) {
                    const int off = 3072 + (ct * 32 + l) * 8;
                    b0 = *(const bf16x8*)&ctf[off];
                    b1 = *(const bf16x8*)&ctf[3840 + off];
                    b2 = *(const bf16x8*)&ctf[7680 + off];
                } else {
                    b0 = bf8zero(); b1 = bf8zero(); b2 = bf8zero();
                }
                acc[ct] = __builtin_amdgcn_mfma_f32_16x16x32_bf16(A2[s], b0, acc[ct], 0, 0, 0);
                acc[ct] = __builtin_amdgcn_mfma_f32_16x16x32_bf16(A1[s], b1, acc[ct], 0, 0, 0);
                acc[ct] = __builtin_amdgcn_mfma_f32_16x16x32_bf16(A0[s], b2, acc[ct], 0, 0, 0);
                acc[ct] = __builtin_amdgcn_mfma_f32_16x16x32_bf16(A1[s], b0, acc[ct], 0, 0, 0);
                acc[ct] = __builtin_amdgcn_mfma_f32_16x16x32_bf16(A0[s], b1, acc[ct], 0, 0, 0);
                acc[ct] = __builtin_amdgcn_mfma_f32_16x16x32_bf16(A0[s], b0, acc[ct], 0, 0, 0);
            }
        }

        #pragma unroll
        for (int i = 0; i < 4; ++i) {
            float n2 = acc[0][i] * acc[0][i];
            n2 = fmaf(acc[1][i], acc[1][i], n2);
            n2 = fmaf(acc[2][i], acc[2][i], n2);
            #pragma unroll
            for (int m = 1; m < 16; m <<= 1) n2 += __shfl_xor(n2, m, 64);
            float inv = 1.0f / fmaxf(sqrtf(n2), 1e-12f);
            const int row_l = rt * 16 + 4 * g + i;
            #pragma unroll
            for (int ct = 0; ct < 3; ++ct)
                xfl[row_l * 49 + ct * 16 + c16] = acc[ct][i] * inv;
        }
    }
    __syncthreads();

    // ---- VQ A-frags: re-split xf (f32-exact) into 3 bf16 terms ----
    bf16x8 X0[4][3], X1[4][3];
    #pragma unroll
    for (int rt = 0; rt < 4; ++rt) {
        const int r0 = rt * 16 + c16;
        {
            const float* p = &xfl[r0 * 49 + 8 * g];
            bf16x8 q0, q1, q2;
            #pragma unroll
            for (int j = 0; j < 8; ++j) {
                short aa, bb, cc;
                bf16split3(p[j], aa, bb, cc);
                q0[j] = aa; q1[j] = bb; q2[j] = cc;
            }
            X0[rt][0] = q0; X0[rt][1] = q1; X0[rt][2] = q2;
        }
        if (g < 2) {
            const float* p = &xfl[r0 * 49 + 32 + 8 * g];
            bf16x8 q0, q1, q2;
            #pragma unroll
            for (int j = 0; j < 8; ++j) {
                short aa, bb, cc;
                bf16split3(p[j], aa, bb, cc);
                q0[j] = aa; q1[j] = bb; q2[j] = cc;
            }
            X1[rt][0] = q0; X1[rt][1] = q1; X1[rt][2] = q2;
        } else {
            X1[rt][0] = bf8zero(); X1[rt][1] = bf8zero(); X1[rt][2] = bf8zero();
        }
    }

    float bd[4][4];
    int   bi[4][4];
    #pragma unroll
    for (int rt = 0; rt < 4; ++rt)
        #pragma unroll
        for (int i = 0; i < 4; ++i) { bd[rt][i] = 3.4e38f; bi[rt][i] = 0; }

    #pragma unroll 1
    for (int ctl = 0; ctl < 8; ++ctl) {
        const int ct = half * 8 + ctl;
        bf16x8 B0[3], B1[3];
        const int off0 = (ct * 64 + l) * 8;
        B0[0] = *(const bf16x8*)&cbf[off0];
        B0[1] = *(const bf16x8*)&cbf[12288 + off0];
        B0[2] = *(const bf16x8*)&cbf[24576 + off0];
        if (l < 32) {
            const int off1 = 8192 + (ct * 32 + l) * 8;
            B1[0] = *(const bf16x8*)&cbf[off1];
            B1[1] = *(const bf16x8*)&cbf[12288 + off1];
            B1[2] = *(const bf16x8*)&cbf[24576 + off1];
        } else {
            B1[0] = bf8zero(); B1[1] = bf8zero(); B1[2] = bf8zero();
        }
        const float cnv = CN[ct * 16 + c16];
        const int idxbase = ct * 16 + c16;
        #pragma unroll
        for (int rt = 0; rt < 4; ++rt) {
            f32x4 a = (f32x4){0.f, 0.f, 0.f, 0.f};
            a = __builtin_amdgcn_mfma_f32_16x16x32_bf16(X0[rt][2], B0[0], a, 0, 0, 0);
            a = __builtin_amdgcn_mfma_f32_16x16x32_bf16(X0[rt][1], B0[1], a, 0, 0, 0);
            a = __builtin_amdgcn_mfma_f32_16x16x32_bf16(X0[rt][0], B0[2], a, 0, 0, 0);
            a = __builtin_amdgcn_mfma_f32_16x16x32_bf16(X1[rt][2], B1[0], a, 0, 0, 0);
            a = __builtin_amdgcn_mfma_f32_16x16x32_bf16(X1[rt][1], B1[1], a, 0, 0, 0);
            a = __builtin_amdgcn_mfma_f32_16x16x32_bf16(X1[rt][0], B1[2], a, 0, 0, 0);
            a = __builtin_amdgcn_mfma_f32_16x16x32_bf16(X0[rt][1], B0[0], a, 0, 0, 0);
            a = __builtin_amdgcn_mfma_f32_16x16x32_bf16(X0[rt][0], B0[1], a, 0, 0, 0);
            a = __builtin_amdgcn_mfma_f32_16x16x32_bf16(X1[rt][1], B1[0], a, 0, 0, 0);
            a = __builtin_amdgcn_mfma_f32_16x16x32_bf16(X1[rt][0], B1[1], a, 0, 0, 0);
            a = __builtin_amdgcn_mfma_f32_16x16x32_bf16(X0[rt][0], B0[0], a, 0, 0, 0);
            a = __builtin_amdgcn_mfma_f32_16x16x32_bf16(X1[rt][0], B1[0], a, 0, 0, 0);
            #pragma unroll
            for (int i = 0; i < 4; ++i) {
                float d = fmaf(-2.f, a[i], cnv);
                if (d < bd[rt][i]) { bd[rt][i] = d; bi[rt][i] = idxbase; }
            }
        }
    }

    if (half == 1) {
        #pragma unroll
        for (int rt = 0; rt < 4; ++rt)
            #pragma unroll
            for (int i = 0; i < 4; ++i) {
                sd[grp][l][rt * 4 + i] = bd[rt][i];
                si[grp][l][rt * 4 + i] = bi[rt][i];
            }
    }
    __syncthreads();
    if (half == 0) {
        float lm = 0.f;
        #pragma unroll
        for (int rt = 0; rt < 4; ++rt) {
            #pragma unroll
            for (int i = 0; i < 4; ++i) {
                float d = bd[rt][i]; int ix = bi[rt][i];
                float dp = sd[grp][l][rt * 4 + i];
                int   ip = si[grp][l][rt * 4 + i];
                if (dp < d || (dp == d && ip < ix)) { d = dp; ix = ip; }
                #pragma unroll
                for (int m = 1; m < 16; m <<= 1) {
                    float d2 = __shfl_xor(d, m, 64);
                    int   i2 = __shfl_xor(ix, m, 64);
                    if (d2 < d || (d2 == d && i2 < ix)) { d = d2; ix = i2; }
                }
                if (c16 == 0) {
                    size_t row = rowbase + rt * 16 + 4 * g + i;
                    out[2 * row + 1] = (float)(ix + KW);
                    lm += d + 1.0f;      // ||xf||^2 == 1
                }
            }
        }
        #pragma unroll
        for (int m = 1; m < 64; m <<= 1) lm += __shfl_xor(lm, m, 64);
        if (l == 0) red2[grp] = lm;
    }
    __syncthreads();
    if (tid == 0) atomicAdd(&sums[1], red2[0] + red2[1]);
}

// LDS histogram over the produced encodings -> global hist[1280].
__global__ __launch_bounds__(256) void hist_kernel(
    const float* __restrict__ out, int* __restrict__ hist)
{
    __shared__ int h[1280];
    const int tid = threadIdx.x;
    for (int i = tid; i < 1280; i += 256) h[i] = 0;
    __syncthreads();
    const int base = blockIdx.x * 1024;
    for (int rr = tid; rr < 1024; rr += 256) {
        const int r = base + rr;
        atomicAdd(&h[(int)out[2 * r]], 1);
        atomicAdd(&h[1024 + ((int)out[2 * r + 1] - KW)], 1);
    }
    __syncthreads();
    for (int i = tid; i < 1280; i += 256)
        if (h[i]) atomicAdd(&hist[i], h[i]);
}

__global__ __launch_bounds__(256) void finalize_kernel(
    const int* __restrict__ hist, const float* __restrict__ sums,
    float* __restrict__ out)
{
    __shared__ float red[4];
    const int tid = threadIdx.x;
    const bool wv = (blockIdx.x == 0);
    const int K = wv ? KW : KM;
    const int base = wv ? 0 : 1024;
    float s = 0.f;
    for (int i = tid; i < K; i += 256) {
        float p = (float)hist[base + i] * (1.0f / 65536.0f);
        s += p * logf(p + 1e-10f);
    }
    #pragma unroll
    for (int off = 32; off >= 1; off >>= 1) s += __shfl_xor(s, off, 64);
    if ((tid & 63) == 0) red[tid >> 6] = s;
    __syncthreads();
    if (tid == 0) {
        float t = red[0] + red[1] + red[2] + red[3];
        float ppl = expf(-t);
        float denom = wv ? (float)(NROWS * DW) : (float)(NROWS * DM);
        int obase = 2 * NROWS + (wv ? 0 : 2);
        out[obase]     = ppl;
        out[obase + 1] = 1.25f * sums[wv ? 0 : 1] / denom;
    }
}

extern "C" void kernel_launch(void* const* d_in, const int* in_sizes, int n_in,
                              void* d_out, int out_size, void* d_ws, size_t ws_size,
                              hipStream_t stream) {
    const float* X   = (const float*)d_in[0];
    const float* cbw = (const float*)d_in[1];
    const float* cbm = (const float*)d_in[2];
    float* out = (float*)d_out;

    char* ws = (char*)d_ws;
    float* sums = (float*)(ws + WS_SUMS);
    int*   hist = (int*)(ws + WS_HIST);
    float* cn_w = (float*)(ws + WS_CNW);
    float* cn_m = (float*)(ws + WS_CNM);
    short* ctf  = (short*)(ws + WS_CTF);
    short* cbf  = (short*)(ws + WS_CBF);
    short* cwh  = (short*)(ws + WS_CWH);
    short* cwl  = (short*)(ws + WS_CWL);

    prep_kernel<<<122, 256, 0, stream>>>(cbw, cbm, sums, hist, cn_w, cn_m,
                                         ctf, cbf, cwh, cwl);
    wave_vq_mfma<<<NROWS / 128, 256, 0, stream>>>(X, cwh, cwl, cn_w, out, sums);
    mfcc_mfma<<<NROWS / 128, 256, 0, stream>>>(X, cn_m, ctf, cbf, out, sums);
    hist_kernel<<<64, 256, 0, stream>>>(out, hist);
    finalize_kernel<<<2, 256, 0, stream>>>(hist, sums, out);
}